// Round 8
// baseline (1116.066 us; speedup 1.0000x reference)
//
#include <hip/hip_runtime.h>
#include <math.h>

#define T_TOK 8192
#define DDIM  1024
#define HDIM  4096
#define NEXP  8
#define BM    256
#define BN1   256
#define BK    32                      /* shorts per K-tile (2 rows packed per 128B LDS line) */
#define MAXROWS (T_TOK*2 + NEXP*BM)   /* 18432 */
#define MAXTILES (MAXROWS/BM)         /* 72 */
#define KS2   2                       /* split-K factor for ffn2 */

typedef __attribute__((ext_vector_type(8))) short short8;
typedef __attribute__((ext_vector_type(4))) short short4v;
typedef __attribute__((ext_vector_type(4))) float f32x4;

typedef const __attribute__((address_space(1))) unsigned int* gp1_t;
typedef __attribute__((address_space(3))) unsigned int* lp3_t;

__device__ __forceinline__ void gld16(const void* g, void* l) {
  __builtin_amdgcn_global_load_lds((gp1_t)g, (lp3_t)l, 16, 0, 0);
}

__device__ __forceinline__ short f2bf(float f) {
  unsigned u = __float_as_uint(f);
  u += 0x7fffu + ((u >> 16) & 1u);   // RNE
  return (short)(u >> 16);
}

// ---------------- x fp32 -> bf16 ----------------
__global__ __launch_bounds__(256) void k_xb(const float* __restrict__ x,
                                            short* __restrict__ xb) {
  size_t i = ((size_t)blockIdx.x * 256 + threadIdx.x) * 8;
  float4 f0 = *(const float4*)&x[i];
  float4 f1 = *(const float4*)&x[i + 4];
  short8 s;
  s[0]=f2bf(f0.x); s[1]=f2bf(f0.y); s[2]=f2bf(f0.z); s[3]=f2bf(f0.w);
  s[4]=f2bf(f1.x); s[5]=f2bf(f1.y); s[6]=f2bf(f1.z); s[7]=f2bf(f1.w);
  *(short8*)&xb[i] = s;
}

// ---------------- weight transpose + fp32->bf16: wt[e][c][r] = w[e][r][c] ----------------
__global__ __launch_bounds__(256) void k_tr(const float* __restrict__ w,
                                            short* __restrict__ wt, int R, int C) {
  __shared__ float sl[64][65];
  int e = blockIdx.z;
  const float* W = w + (size_t)e * R * C;
  short* O = wt + (size_t)e * R * C;
  int c0 = blockIdx.x * 64, r0 = blockIdx.y * 64;
  int t = threadIdx.x;
  int lr = t >> 4, lc4 = (t & 15) * 4;
#pragma unroll
  for (int i = 0; i < 4; i++) {
    float4 v = *(const float4*)&W[(size_t)(r0 + lr + i * 16) * C + c0 + lc4];
    sl[lr + i * 16][lc4 + 0] = v.x;
    sl[lr + i * 16][lc4 + 1] = v.y;
    sl[lr + i * 16][lc4 + 2] = v.z;
    sl[lr + i * 16][lc4 + 3] = v.w;
  }
  __syncthreads();
#pragma unroll
  for (int i = 0; i < 4; i++) {
    int oc = lr + i * 16;
    short4v s;
#pragma unroll
    for (int j = 0; j < 4; j++) s[j] = f2bf(sl[lc4 + j][oc]);
    *(short4v*)&O[(size_t)(c0 + oc) * R + r0 + lc4] = s;
  }
}

// ---------------- gating (fp32 x for exact top-k selection) ----------------
__global__ __launch_bounds__(256) void k_gate(const float* __restrict__ x,
    const float* __restrict__ gw, const float* __restrict__ gb,
    int2* __restrict__ toke, float2* __restrict__ tokw, int* __restrict__ cnt) {
  __shared__ float sg[NEXP * DDIM];
  for (int i = threadIdx.x; i < NEXP * DDIM; i += 256) {
    int e = i >> 10, d = i & (DDIM - 1);
    sg[i] = gw[d * NEXP + e];
  }
  __syncthreads();
  int wave = threadIdx.x >> 6, lane = threadIdx.x & 63;
  int tok0 = blockIdx.x * 32;
  for (int tt = wave; tt < 32; tt += 4) {
    int tok = tok0 + tt;
    float p[NEXP];
#pragma unroll
    for (int e = 0; e < NEXP; e++) p[e] = 0.f;
#pragma unroll
    for (int c = 0; c < 4; c++) {
      int d = c * 256 + lane * 4;
      float4 xv = *(const float4*)&x[(size_t)tok * DDIM + d];
#pragma unroll
      for (int e = 0; e < NEXP; e++) {
        float4 g = *(const float4*)&sg[e * DDIM + d];
        p[e] += xv.x * g.x + xv.y * g.y + xv.z * g.z + xv.w * g.w;
      }
    }
#pragma unroll
    for (int off = 32; off; off >>= 1)
#pragma unroll
      for (int e = 0; e < NEXP; e++) p[e] += __shfl_xor(p[e], off);
    if (lane == 0) {
      float l[NEXP];
#pragma unroll
      for (int e = 0; e < NEXP; e++) l[e] = p[e] + gb[e];
      int i0 = 0;
#pragma unroll
      for (int e = 1; e < NEXP; e++) if (l[e] > l[i0]) i0 = e;
      int i1 = (i0 == 0) ? 1 : 0;
#pragma unroll
      for (int e = 0; e < NEXP; e++) if (e != i0 && l[e] > l[i1]) i1 = e;
      float ex = expf(l[i1] - l[i0]);
      float w0 = 1.f / (1.f + ex);
      toke[tok] = make_int2(i0, i1);
      tokw[tok] = make_float2(w0, 1.f - w0);
      atomicAdd(&cnt[i0], 1);
      atomicAdd(&cnt[i1], 1);
    }
  }
}

// ---------------- routing plan ----------------
__global__ void k_plan(const int* __restrict__ cnt, int* __restrict__ pbase,
                       int* __restrict__ texp) {
  if (threadIdx.x == 0 && blockIdx.x == 0) {
    int base = 0;
    for (int e = 0; e < NEXP; e++) {
      pbase[e] = base;
      int pc = (cnt[e] + BM - 1) & ~(BM - 1);
      for (int t = base / BM; t < (base + pc) / BM; ++t) texp[t] = e;
      base += pc;
    }
    for (int t = base / BM; t < MAXTILES; ++t) texp[t] = -1;
  }
}

__global__ __launch_bounds__(256) void k_scatter(const int2* __restrict__ toke,
    const float2* __restrict__ tokw, const int* __restrict__ pbase,
    int* __restrict__ fill, int* __restrict__ rtok, float* __restrict__ rwgt) {
  int tok = blockIdx.x * 256 + threadIdx.x;
  if (tok >= T_TOK) return;
  int2 te = toke[tok];
  float2 tw = tokw[tok];
  int s0 = atomicAdd(&fill[te.x], 1);
  rtok[pbase[te.x] + s0] = tok; rwgt[pbase[te.x] + s0] = tw.x;
  int s1 = atomicAdd(&fill[te.y], 1);
  rtok[pbase[te.y] + s1] = tok; rwgt[pbase[te.y] + s1] = tw.y;
}

// ======================= 2-phase grouped GEMM (64 KiB LDS, 2 blocks/CU) ==========
// LDS: per operand 128 lines x 128B; line L holds rows {2L, 2L+1} as 8 16B slots,
// logical slot s of line L stored at phys slot s^(L&7)  (same phys pattern as the
// proven BK=64 XOR-8 layout -> 0 bank conflicts). Staging: per wave 2 gld16 per
// operand, per-lane inverse-swizzled global source (rule #21), linear LDS dest.
// K-loop: STAGE(next) -> vmcnt(4) -> barrier -> 32 MFMA -> barrier. Counted vmcnt:
// this tile's 4 loads/wave stay in flight; co-resident block covers the residual.

#define BARR { __builtin_amdgcn_s_barrier(); __builtin_amdgcn_sched_barrier(0); }

#define STG(bf, ko) { \
  gld16(sA[0] + (ko), &AL[bf][(wid * 32 + 0) * BK]); \
  gld16(sA[1] + (ko), &AL[bf][(wid * 32 + 16) * BK]); \
  gld16(sB[0] + (ko), &BL[bf][(wid * 32 + 0) * BK]); \
  gld16(sB[1] + (ko), &BL[bf][(wid * 32 + 16) * BK]); }

#define RD_MM(cur) { \
  short8 af[8], bg[4]; \
  _Pragma("unroll") \
  for (int i = 0; i < 8; i++) af[i] = *(short8*)&AL[cur][(wm2 + i * 8 + lr2) * 64 + xsl8]; \
  _Pragma("unroll") \
  for (int j = 0; j < 4; j++) bg[j] = *(short8*)&BL[cur][(wn2 + j * 8 + lr2) * 64 + xsl8]; \
  __builtin_amdgcn_s_setprio(1); \
  _Pragma("unroll") \
  for (int i = 0; i < 8; i++) \
  _Pragma("unroll") \
  for (int j = 0; j < 4; j++) \
    acc[i][j] = __builtin_amdgcn_mfma_f32_16x16x32_bf16(af[i], bg[j], acc[i][j], 0, 0, 0); \
  __builtin_amdgcn_s_setprio(0); }

#define GEMM_LOOP(NKv) \
  STG(0, 0); \
  asm volatile("s_waitcnt vmcnt(0)" ::: "memory"); \
  BARR; \
  for (int t = 0; t < (NKv); ++t) { \
    int cur = t & 1; \
    if (t + 1 < (NKv)) { \
      STG(cur ^ 1, (t + 1) * BK); \
      asm volatile("s_waitcnt vmcnt(4)" ::: "memory"); \
    } else { \
      asm volatile("s_waitcnt vmcnt(0)" ::: "memory"); \
    } \
    BARR; \
    RD_MM(cur); \
    __builtin_amdgcn_sched_barrier(0); \
    BARR; \
  }

// ---------------- stage 1: h = gelu(x @ w1[e] + b1[e]) ----------------
// grid (HDIM/256 = 16, nt), 512 threads (8 waves, 2x4). w1t = [e][n(H)][k(D)] bf16.
__global__ __launch_bounds__(512) void k_ffn1(const short* __restrict__ xb,
    const short* __restrict__ w1t, const float* __restrict__ b1,
    const int* __restrict__ rtok, const int* __restrict__ texp,
    int tile_base, short* __restrict__ hbuf) {
  int tl = blockIdx.y;
  int tm = tile_base + tl;
  int e = texp[tm];
  if (e < 0) return;
  int n0 = blockIdx.x * BN1;
  const short* W = w1t + (size_t)e * HDIM * DDIM;
  __shared__ short AL[2][BM * BK];   // 16 KiB each buffer
  __shared__ short BL[2][BM * BK];
  int t = threadIdx.x, wid = t >> 6, lane = t & 63;
  // staging: lane -> logical (row-in-16, 16B slot) with inverse swizzle
  int sl  = (lane & 7) ^ (lane >> 3);          // logical slot 0..7 within line pair
  int rloc = ((lane >> 3) << 1) + (sl >> 2);   // row offset 0..15
  int c16  = (sl & 3) * 8;                     // shorts offset within 32-short row
  const short* sA[2]; const short* sB[2];
#pragma unroll
  for (int i = 0; i < 2; i++) {
    int rl_ = wid * 32 + i * 16 + rloc;
    int tok = rtok[tm * BM + rl_]; if (tok < 0) tok = 0;   // pads read row0 (dropped in ffn2)
    sA[i] = xb + (size_t)tok * DDIM + c16;
    sB[i] = W + (size_t)(n0 + rl_) * DDIM + c16;
  }

  f32x4 acc[8][4];
#pragma unroll
  for (int i = 0; i < 8; i++)
#pragma unroll
    for (int j = 0; j < 4; j++) acc[i][j] = (f32x4){0.f, 0.f, 0.f, 0.f};

  int wm = (wid >> 2) * 128, wn = (wid & 3) * 64;
  int lr = lane & 15, kg = lane >> 4;
  int wm2 = wm >> 1, wn2 = wn >> 1, lr2 = lr >> 1;
  int xsl8 = ((((lr & 1) << 2) | kg) ^ (lr2 & 7)) << 3;   // swizzled phys slot * 8 shorts

  GEMM_LOOP(DDIM / BK)   // 32

#pragma unroll
  for (int j = 0; j < 4; j++) {
    int gcol = n0 + wn + j * 16 + lr;
    float bias = b1[e * HDIM + gcol];
#pragma unroll
    for (int i = 0; i < 8; i++) {
      int rl = wm + i * 16 + kg * 4;
#pragma unroll
      for (int r = 0; r < 4; r++) {
        float v = acc[i][j][r] + bias;
        v = 0.5f * v * (1.f + erff(v * 0.70710678118f));
        hbuf[(size_t)(tl * BM + rl + r) * HDIM + gcol] = f2bf(v);
      }
    }
  }
}

// ---------------- stage 2: out[tok] += wgt * (h @ w2[e] + b2[e]) ----------------
// grid (DDIM/256 = 4, KS2, nt), 512 threads. w2t = [e][n(D)][k(H)] bf16. Split-K over H.
__global__ __launch_bounds__(512) void k_ffn2(const short* __restrict__ hbuf,
    const short* __restrict__ w2t, const float* __restrict__ b2,
    const int* __restrict__ rtok, const float* __restrict__ rwgt,
    const int* __restrict__ texp, int tile_base, float* __restrict__ out) {
  int tl = blockIdx.z;
  int tm = tile_base + tl;
  int e = texp[tm];
  if (e < 0) return;
  int kc = blockIdx.y;
  int n0 = blockIdx.x * BN1;
  const short* W = w2t + (size_t)e * DDIM * HDIM;
  __shared__ short AL[2][BM * BK];
  __shared__ short BL[2][BM * BK];
  int t = threadIdx.x, wid = t >> 6, lane = t & 63;
  int sl  = (lane & 7) ^ (lane >> 3);
  int rloc = ((lane >> 3) << 1) + (sl >> 2);
  int c16  = (sl & 3) * 8;
  const int NK = HDIM / BK / KS2;            // 64
  int kbase = kc * NK * BK;
  const short* sA[2]; const short* sB[2];
#pragma unroll
  for (int i = 0; i < 2; i++) {
    int rl_ = wid * 32 + i * 16 + rloc;
    sA[i] = hbuf + (size_t)(tl * BM + rl_) * HDIM + kbase + c16;
    sB[i] = W + (size_t)(n0 + rl_) * HDIM + kbase + c16;
  }

  f32x4 acc[8][4];
#pragma unroll
  for (int i = 0; i < 8; i++)
#pragma unroll
    for (int j = 0; j < 4; j++) acc[i][j] = (f32x4){0.f, 0.f, 0.f, 0.f};

  int wm = (wid >> 2) * 128, wn = (wid & 3) * 64;
  int lr = lane & 15, kg = lane >> 4;
  int wm2 = wm >> 1, wn2 = wn >> 1, lr2 = lr >> 1;
  int xsl8 = ((((lr & 1) << 2) | kg) ^ (lr2 & 7)) << 3;

  GEMM_LOOP(NK)

#pragma unroll
  for (int j = 0; j < 4; j++) {
    int gcol = n0 + wn + j * 16 + lr;
    float bias = (kc == 0) ? b2[e * DDIM + gcol] : 0.f;
#pragma unroll
    for (int i = 0; i < 8; i++) {
      int rl = wm + i * 16 + kg * 4;
#pragma unroll
      for (int r = 0; r < 4; r++) {
        int grow = tm * BM + rl + r;
        int tok = rtok[grow];
        if (tok >= 0) {
          float v = (acc[i][j][r] + bias) * rwgt[grow];
          atomicAdd(&out[(size_t)tok * DDIM + gcol], v);
        }
      }
    }
  }
}

extern "C" void kernel_launch(void* const* d_in, const int* in_sizes, int n_in,
                              void* d_out, int out_size, void* d_ws, size_t ws_size,
                              hipStream_t stream) {
  const float* x  = (const float*)d_in[0];
  const float* gw = (const float*)d_in[1];
  const float* gb = (const float*)d_in[2];
  const float* w1 = (const float*)d_in[3];
  const float* b1 = (const float*)d_in[4];
  const float* w2 = (const float*)d_in[5];
  const float* b2 = (const float*)d_in[6];
  float* out = (float*)d_out;
  char* ws = (char*)d_ws;

  // ws layout: 1MB header | w1t 67.1MB | w2t 67.1MB | xb 16.8MB | hbuf (chunked)
  int*    cnt   = (int*)(ws + 0);
  int*    fill  = (int*)(ws + 32);
  int*    pbase = (int*)(ws + 64);
  int*    texp  = (int*)(ws + 128);
  int*    rtok  = (int*)(ws + 1024);
  float*  rwgt  = (float*)(ws + 1024 + (size_t)MAXROWS * 4);
  int2*   toke  = (int2*)(ws + 1024 + (size_t)MAXROWS * 8);
  float2* tokw  = (float2*)(ws + 1024 + (size_t)MAXROWS * 8 + (size_t)T_TOK * 8);
  size_t wbytes = (size_t)NEXP * DDIM * HDIM * 2;
  short*  w1t   = (short*)(ws + (1 << 20));
  short*  w2t   = (short*)(ws + (1 << 20) + wbytes);
  short*  xb    = (short*)(ws + (1 << 20) + 2 * wbytes);
  size_t hoff   = (1 << 20) + 2 * wbytes + (size_t)T_TOK * DDIM * 2;
  short*  hbuf  = (short*)(ws + hoff);

  size_t hcap = ws_size > hoff ? ws_size - hoff : 0;
  int tpc = (int)(hcap / ((size_t)BM * HDIM * 2));   // 2MB per tile of h
  if (tpc < 1) return;
  if (tpc > MAXTILES) tpc = MAXTILES;

  hipMemsetAsync(d_out, 0, (size_t)T_TOK * DDIM * 4, stream);
  hipMemsetAsync(ws, 0, 128, stream);
  hipMemsetAsync(rtok, 0xFF, (size_t)MAXROWS * 4, stream);

  k_tr<<<dim3(HDIM / 64, DDIM / 64, NEXP), 256, 0, stream>>>(w1, w1t, DDIM, HDIM);
  k_tr<<<dim3(DDIM / 64, HDIM / 64, NEXP), 256, 0, stream>>>(w2, w2t, HDIM, DDIM);
  k_xb<<<(T_TOK * DDIM) / (256 * 8), 256, 0, stream>>>(x, xb);

  k_gate<<<256, 256, 0, stream>>>(x, gw, gb, toke, tokw, cnt);
  k_plan<<<1, 64, 0, stream>>>(cnt, pbase, texp);
  k_scatter<<<T_TOK / 256, 256, 0, stream>>>(toke, tokw, pbase, fill, rtok, rwgt);

  for (int base = 0; base < MAXTILES; base += tpc) {
    int nt = MAXTILES - base;
    if (nt > tpc) nt = tpc;
    k_ffn1<<<dim3(HDIM / BN1, nt), 512, 0, stream>>>(xb, w1t, b1, rtok, texp, base, hbuf);
    k_ffn2<<<dim3(DDIM / BN1, KS2, nt), 512, 0, stream>>>(hbuf, w2t, b2, rtok, rwgt, texp, base, out);
  }
}

// Round 9
// 917.202 us; speedup vs baseline: 1.2168x; 1.2168x over previous
//
#include <hip/hip_runtime.h>
#include <math.h>

#define T_TOK 8192
#define DDIM  1024
#define HDIM  4096
#define NEXP  8
#define BM    256
#define BN    128
#define BK    64                      /* shorts per K-tile */
#define MAXROWS (T_TOK*2 + NEXP*BM)   /* 18432 */
#define MAXTILES (MAXROWS/BM)         /* 72 */
#define KS2   2                       /* split-K factor for ffn2 */

typedef __attribute__((ext_vector_type(8))) short short8;
typedef __attribute__((ext_vector_type(4))) short short4v;
typedef __attribute__((ext_vector_type(4))) float f32x4;

typedef const __attribute__((address_space(1))) unsigned int* gp1_t;
typedef __attribute__((address_space(3))) unsigned int* lp3_t;

__device__ __forceinline__ void gld16(const void* g, void* l) {
  __builtin_amdgcn_global_load_lds((gp1_t)g, (lp3_t)l, 16, 0, 0);
}

__device__ __forceinline__ short f2bf(float f) {
  unsigned u = __float_as_uint(f);
  u += 0x7fffu + ((u >> 16) & 1u);   // RNE
  return (short)(u >> 16);
}

// ---------------- x fp32 -> bf16 ----------------
__global__ __launch_bounds__(256) void k_xb(const float* __restrict__ x,
                                            short* __restrict__ xb) {
  size_t i = ((size_t)blockIdx.x * 256 + threadIdx.x) * 8;
  float4 f0 = *(const float4*)&x[i];
  float4 f1 = *(const float4*)&x[i + 4];
  short8 s;
  s[0]=f2bf(f0.x); s[1]=f2bf(f0.y); s[2]=f2bf(f0.z); s[3]=f2bf(f0.w);
  s[4]=f2bf(f1.x); s[5]=f2bf(f1.y); s[6]=f2bf(f1.z); s[7]=f2bf(f1.w);
  *(short8*)&xb[i] = s;
}

// ---------------- weight transpose + fp32->bf16: wt[e][c][r] = w[e][r][c] ----------------
__global__ __launch_bounds__(256) void k_tr(const float* __restrict__ w,
                                            short* __restrict__ wt, int R, int C) {
  __shared__ float sl[64][65];
  int e = blockIdx.z;
  const float* W = w + (size_t)e * R * C;
  short* O = wt + (size_t)e * R * C;
  int c0 = blockIdx.x * 64, r0 = blockIdx.y * 64;
  int t = threadIdx.x;
  int lr = t >> 4, lc4 = (t & 15) * 4;
#pragma unroll
  for (int i = 0; i < 4; i++) {
    float4 v = *(const float4*)&W[(size_t)(r0 + lr + i * 16) * C + c0 + lc4];
    sl[lr + i * 16][lc4 + 0] = v.x;
    sl[lr + i * 16][lc4 + 1] = v.y;
    sl[lr + i * 16][lc4 + 2] = v.z;
    sl[lr + i * 16][lc4 + 3] = v.w;
  }
  __syncthreads();
#pragma unroll
  for (int i = 0; i < 4; i++) {
    int oc = lr + i * 16;
    short4v s;
#pragma unroll
    for (int j = 0; j < 4; j++) s[j] = f2bf(sl[lc4 + j][oc]);
    *(short4v*)&O[(size_t)(c0 + oc) * R + r0 + lc4] = s;
  }
}

// ---------------- gating (fp32 x for exact top-k selection) ----------------
__global__ __launch_bounds__(256) void k_gate(const float* __restrict__ x,
    const float* __restrict__ gw, const float* __restrict__ gb,
    int2* __restrict__ toke, float2* __restrict__ tokw, int* __restrict__ cnt) {
  __shared__ float sg[NEXP * DDIM];
  for (int i = threadIdx.x; i < NEXP * DDIM; i += 256) {
    int e = i >> 10, d = i & (DDIM - 1);
    sg[i] = gw[d * NEXP + e];
  }
  __syncthreads();
  int wave = threadIdx.x >> 6, lane = threadIdx.x & 63;
  int tok0 = blockIdx.x * 32;
  for (int tt = wave; tt < 32; tt += 4) {
    int tok = tok0 + tt;
    float p[NEXP];
#pragma unroll
    for (int e = 0; e < NEXP; e++) p[e] = 0.f;
#pragma unroll
    for (int c = 0; c < 4; c++) {
      int d = c * 256 + lane * 4;
      float4 xv = *(const float4*)&x[(size_t)tok * DDIM + d];
#pragma unroll
      for (int e = 0; e < NEXP; e++) {
        float4 g = *(const float4*)&sg[e * DDIM + d];
        p[e] += xv.x * g.x + xv.y * g.y + xv.z * g.z + xv.w * g.w;
      }
    }
#pragma unroll
    for (int off = 32; off; off >>= 1)
#pragma unroll
      for (int e = 0; e < NEXP; e++) p[e] += __shfl_xor(p[e], off);
    if (lane == 0) {
      float l[NEXP];
#pragma unroll
      for (int e = 0; e < NEXP; e++) l[e] = p[e] + gb[e];
      int i0 = 0;
#pragma unroll
      for (int e = 1; e < NEXP; e++) if (l[e] > l[i0]) i0 = e;
      int i1 = (i0 == 0) ? 1 : 0;
#pragma unroll
      for (int e = 0; e < NEXP; e++) if (e != i0 && l[e] > l[i1]) i1 = e;
      float ex = expf(l[i1] - l[i0]);
      float w0 = 1.f / (1.f + ex);
      toke[tok] = make_int2(i0, i1);
      tokw[tok] = make_float2(w0, 1.f - w0);
      atomicAdd(&cnt[i0], 1);
      atomicAdd(&cnt[i1], 1);
    }
  }
}

// ---------------- routing plan ----------------
__global__ void k_plan(const int* __restrict__ cnt, int* __restrict__ pbase,
                       int* __restrict__ texp) {
  if (threadIdx.x == 0 && blockIdx.x == 0) {
    int base = 0;
    for (int e = 0; e < NEXP; e++) {
      pbase[e] = base;
      int pc = (cnt[e] + BM - 1) & ~(BM - 1);
      for (int t = base / BM; t < (base + pc) / BM; ++t) texp[t] = e;
      base += pc;
    }
    for (int t = base / BM; t < MAXTILES; ++t) texp[t] = -1;
  }
}

__global__ __launch_bounds__(256) void k_scatter(const int2* __restrict__ toke,
    const float2* __restrict__ tokw, const int* __restrict__ pbase,
    int* __restrict__ fill, int* __restrict__ rtok, float* __restrict__ rwgt) {
  int tok = blockIdx.x * 256 + threadIdx.x;
  if (tok >= T_TOK) return;
  int2 te = toke[tok];
  float2 tw = tokw[tok];
  int s0 = atomicAdd(&fill[te.x], 1);
  rtok[pbase[te.x] + s0] = tok; rwgt[pbase[te.x] + s0] = tw.x;
  int s1 = atomicAdd(&fill[te.y], 1);
  rtok[pbase[te.y] + s1] = tok; rwgt[pbase[te.y] + s1] = tw.y;
}

// ============== 256x128-tile grouped GEMM, 8 waves (4M x 2N, 64x64/wave) ==========
// acc[4][4] = 64 AGPR; __launch_bounds__(512,4) caps arch+acc <= 128 regs/wave
// -> 4 waves/SIMD -> 2 co-resident blocks/CU (the m97/m114 implicit-overlap regime).
// LDS single-buffered 48 KiB: A[256][64] + B[128][64] shorts, XOR-8 swizzled slots
// (16B slot s of row r holds global slot s^(r&7); proven 0 bank conflicts).
// Simple loop: STAGE (6 gld16/wave) -> vmcnt(0) -> barrier -> 32 MFMA -> barrier;
// co-resident block covers the drain.

#define STG(ko) { \
  gld16(sA[0] + (ko), &AL[(0 * 64 + wid * 8) * BK]); \
  gld16(sA[1] + (ko), &AL[(1 * 64 + wid * 8) * BK]); \
  gld16(sA[2] + (ko), &AL[(2 * 64 + wid * 8) * BK]); \
  gld16(sA[3] + (ko), &AL[(3 * 64 + wid * 8) * BK]); \
  gld16(sB[0] + (ko), &BL[(0 * 64 + wid * 8) * BK]); \
  gld16(sB[1] + (ko), &BL[(1 * 64 + wid * 8) * BK]); }

#define MFMA_TILE { \
  _Pragma("unroll") \
  for (int s = 0; s < 2; ++s) { \
    int xo = ((s * 4 + kg) ^ x7) << 3; \
    short8 af[4], bg[4]; \
    _Pragma("unroll") \
    for (int i = 0; i < 4; i++) af[i] = *(short8*)&AL[(wm + i * 16 + lr) * BK + xo]; \
    _Pragma("unroll") \
    for (int j = 0; j < 4; j++) bg[j] = *(short8*)&BL[(wn + j * 16 + lr) * BK + xo]; \
    _Pragma("unroll") \
    for (int i = 0; i < 4; i++) \
    _Pragma("unroll") \
    for (int j = 0; j < 4; j++) \
      acc[i][j] = __builtin_amdgcn_mfma_f32_16x16x32_bf16(af[i], bg[j], acc[i][j], 0, 0, 0); \
  } }

#define GEMM_LOOP(NKv) \
  for (int kt = 0; kt < (NKv); ++kt) { \
    STG(kt * BK); \
    asm volatile("s_waitcnt vmcnt(0)" ::: "memory"); \
    __syncthreads(); \
    MFMA_TILE; \
    __syncthreads(); \
  }

// ---------------- stage 1: h = gelu(x @ w1[e] + b1[e]) ----------------
// grid (HDIM/128 = 32, nt), 512 threads. w1t = [e][n(H)][k(D)] bf16.
__global__ __launch_bounds__(512, 4) void k_ffn1(const short* __restrict__ xb,
    const short* __restrict__ w1t, const float* __restrict__ b1,
    const int* __restrict__ rtok, const int* __restrict__ texp,
    int tile_base, short* __restrict__ hbuf) {
  int tl = blockIdx.y;
  int tm = tile_base + tl;
  int e = texp[tm];
  if (e < 0) return;
  int n0 = blockIdx.x * BN;
  const short* W = w1t + (size_t)e * HDIM * DDIM;
  __shared__ short AL[BM * BK];   // 32 KiB
  __shared__ short BL[BN * BK];   // 16 KiB
  int t = threadIdx.x, wid = t >> 6, lane = t & 63;
  int sr8 = lane >> 3, slot = lane & 7;
  int swz = (slot ^ sr8) * 8;
  const short* sA[4]; const short* sB[2];
#pragma unroll
  for (int i = 0; i < 4; i++) {
    int r = i * 64 + wid * 8 + sr8;
    int tok = rtok[tm * BM + r]; if (tok < 0) tok = 0;   // pads read row0 (dropped in ffn2)
    sA[i] = xb + (size_t)tok * DDIM + swz;
  }
#pragma unroll
  for (int i = 0; i < 2; i++) {
    int r = i * 64 + wid * 8 + sr8;
    sB[i] = W + (size_t)(n0 + r) * DDIM + swz;
  }

  f32x4 acc[4][4];
#pragma unroll
  for (int i = 0; i < 4; i++)
#pragma unroll
    for (int j = 0; j < 4; j++) acc[i][j] = (f32x4){0.f, 0.f, 0.f, 0.f};

  int wm = (wid & 3) * 64, wn = (wid >> 2) * 64;
  int lr = lane & 15, kg = lane >> 4, x7 = lr & 7;

  GEMM_LOOP(DDIM / BK)   // 16

#pragma unroll
  for (int j = 0; j < 4; j++) {
    int gcol = n0 + wn + j * 16 + lr;
    float bias = b1[e * HDIM + gcol];
#pragma unroll
    for (int i = 0; i < 4; i++) {
      int rl = wm + i * 16 + kg * 4;
#pragma unroll
      for (int r = 0; r < 4; r++) {
        float v = acc[i][j][r] + bias;
        v = 0.5f * v * (1.f + erff(v * 0.70710678118f));
        hbuf[(size_t)(tl * BM + rl + r) * HDIM + gcol] = f2bf(v);
      }
    }
  }
}

// ---------------- stage 2: out[tok] += wgt * (h @ w2[e] + b2[e]) ----------------
// grid (DDIM/128 = 8, KS2, nt), 512 threads. w2t = [e][n(D)][k(H)] bf16. Split-K over H.
__global__ __launch_bounds__(512, 4) void k_ffn2(const short* __restrict__ hbuf,
    const short* __restrict__ w2t, const float* __restrict__ b2,
    const int* __restrict__ rtok, const float* __restrict__ rwgt,
    const int* __restrict__ texp, int tile_base, float* __restrict__ out) {
  int tl = blockIdx.z;
  int tm = tile_base + tl;
  int e = texp[tm];
  if (e < 0) return;
  int kc = blockIdx.y;
  int n0 = blockIdx.x * BN;
  const short* W = w2t + (size_t)e * DDIM * HDIM;
  __shared__ short AL[BM * BK];
  __shared__ short BL[BN * BK];
  int t = threadIdx.x, wid = t >> 6, lane = t & 63;
  int sr8 = lane >> 3, slot = lane & 7;
  int swz = (slot ^ sr8) * 8;
  const int NK = HDIM / BK / KS2;            // 16
  int kbase = kc * NK * BK;
  const short* sA[4]; const short* sB[2];
#pragma unroll
  for (int i = 0; i < 4; i++) {
    int r = i * 64 + wid * 8 + sr8;
    sA[i] = hbuf + (size_t)(tl * BM + r) * HDIM + kbase + swz;
  }
#pragma unroll
  for (int i = 0; i < 2; i++) {
    int r = i * 64 + wid * 8 + sr8;
    sB[i] = W + (size_t)(n0 + r) * HDIM + kbase + swz;
  }

  f32x4 acc[4][4];
#pragma unroll
  for (int i = 0; i < 4; i++)
#pragma unroll
    for (int j = 0; j < 4; j++) acc[i][j] = (f32x4){0.f, 0.f, 0.f, 0.f};

  int wm = (wid & 3) * 64, wn = (wid >> 2) * 64;
  int lr = lane & 15, kg = lane >> 4, x7 = lr & 7;

  GEMM_LOOP(NK)

#pragma unroll
  for (int j = 0; j < 4; j++) {
    int gcol = n0 + wn + j * 16 + lr;
    float bias = (kc == 0) ? b2[e * DDIM + gcol] : 0.f;
#pragma unroll
    for (int i = 0; i < 4; i++) {
      int rl = wm + i * 16 + kg * 4;
#pragma unroll
      for (int r = 0; r < 4; r++) {
        int grow = tm * BM + rl + r;
        int tok = rtok[grow];
        if (tok >= 0) {
          float v = (acc[i][j][r] + bias) * rwgt[grow];
          atomicAdd(&out[(size_t)tok * DDIM + gcol], v);
        }
      }
    }
  }
}

extern "C" void kernel_launch(void* const* d_in, const int* in_sizes, int n_in,
                              void* d_out, int out_size, void* d_ws, size_t ws_size,
                              hipStream_t stream) {
  const float* x  = (const float*)d_in[0];
  const float* gw = (const float*)d_in[1];
  const float* gb = (const float*)d_in[2];
  const float* w1 = (const float*)d_in[3];
  const float* b1 = (const float*)d_in[4];
  const float* w2 = (const float*)d_in[5];
  const float* b2 = (const float*)d_in[6];
  float* out = (float*)d_out;
  char* ws = (char*)d_ws;

  // ws layout: 1MB header | w1t 67.1MB | w2t 67.1MB | xb 16.8MB | hbuf (chunked)
  int*    cnt   = (int*)(ws + 0);
  int*    fill  = (int*)(ws + 32);
  int*    pbase = (int*)(ws + 64);
  int*    texp  = (int*)(ws + 128);
  int*    rtok  = (int*)(ws + 1024);
  float*  rwgt  = (float*)(ws + 1024 + (size_t)MAXROWS * 4);
  int2*   toke  = (int2*)(ws + 1024 + (size_t)MAXROWS * 8);
  float2* tokw  = (float2*)(ws + 1024 + (size_t)MAXROWS * 8 + (size_t)T_TOK * 8);
  size_t wbytes = (size_t)NEXP * DDIM * HDIM * 2;
  short*  w1t   = (short*)(ws + (1 << 20));
  short*  w2t   = (short*)(ws + (1 << 20) + wbytes);
  short*  xb    = (short*)(ws + (1 << 20) + 2 * wbytes);
  size_t hoff   = (1 << 20) + 2 * wbytes + (size_t)T_TOK * DDIM * 2;
  short*  hbuf  = (short*)(ws + hoff);

  size_t hcap = ws_size > hoff ? ws_size - hoff : 0;
  int tpc = (int)(hcap / ((size_t)BM * HDIM * 2));   // 2MB per tile of h
  if (tpc < 1) return;
  if (tpc > MAXTILES) tpc = MAXTILES;

  hipMemsetAsync(d_out, 0, (size_t)T_TOK * DDIM * 4, stream);
  hipMemsetAsync(ws, 0, 128, stream);
  hipMemsetAsync(rtok, 0xFF, (size_t)MAXROWS * 4, stream);

  k_tr<<<dim3(HDIM / 64, DDIM / 64, NEXP), 256, 0, stream>>>(w1, w1t, DDIM, HDIM);
  k_tr<<<dim3(DDIM / 64, HDIM / 64, NEXP), 256, 0, stream>>>(w2, w2t, HDIM, DDIM);
  k_xb<<<(T_TOK * DDIM) / (256 * 8), 256, 0, stream>>>(x, xb);

  k_gate<<<256, 256, 0, stream>>>(x, gw, gb, toke, tokw, cnt);
  k_plan<<<1, 64, 0, stream>>>(cnt, pbase, texp);
  k_scatter<<<T_TOK / 256, 256, 0, stream>>>(toke, tokw, pbase, fill, rtok, rwgt);

  for (int base = 0; base < MAXTILES; base += tpc) {
    int nt = MAXTILES - base;
    if (nt > tpc) nt = tpc;
    k_ffn1<<<dim3(HDIM / BN, nt), 512, 0, stream>>>(xb, w1t, b1, rtok, texp, base, hbuf);
    k_ffn2<<<dim3(DDIM / BN, KS2, nt), 512, 0, stream>>>(hbuf, w2t, b2, rtok, rwgt, texp, base, out);
  }
}

// Round 10
// 855.177 us; speedup vs baseline: 1.3051x; 1.0725x over previous
//
#include <hip/hip_runtime.h>
#include <math.h>

#define T_TOK 8192
#define DDIM  1024
#define HDIM  4096
#define NEXP  8
#define BM    128                     /* row tile */
#define BN    128                     /* col tile */
#define BK    64                      /* shorts per K-tile */
#define MAXROWS (T_TOK*2 + NEXP*BM)   /* 17408 */
#define MAXTILES (MAXROWS/BM)         /* 136 */
#define KS2   2                       /* split-K factor for ffn2 */

typedef __attribute__((ext_vector_type(8))) short short8;
typedef __attribute__((ext_vector_type(4))) short short4v;
typedef __attribute__((ext_vector_type(4))) float f32x4;

typedef const __attribute__((address_space(1))) unsigned int* gp1_t;
typedef __attribute__((address_space(3))) unsigned int* lp3_t;

__device__ __forceinline__ void gld16(const void* g, void* l) {
  __builtin_amdgcn_global_load_lds((gp1_t)g, (lp3_t)l, 16, 0, 0);
}

__device__ __forceinline__ short f2bf(float f) {
  unsigned u = __float_as_uint(f);
  u += 0x7fffu + ((u >> 16) & 1u);   // RNE
  return (short)(u >> 16);
}

// ---------------- x fp32 -> bf16 ----------------
__global__ __launch_bounds__(256) void k_xb(const float* __restrict__ x,
                                            short* __restrict__ xb) {
  size_t i = ((size_t)blockIdx.x * 256 + threadIdx.x) * 8;
  float4 f0 = *(const float4*)&x[i];
  float4 f1 = *(const float4*)&x[i + 4];
  short8 s;
  s[0]=f2bf(f0.x); s[1]=f2bf(f0.y); s[2]=f2bf(f0.z); s[3]=f2bf(f0.w);
  s[4]=f2bf(f1.x); s[5]=f2bf(f1.y); s[6]=f2bf(f1.z); s[7]=f2bf(f1.w);
  *(short8*)&xb[i] = s;
}

// ---------------- weight transpose + fp32->bf16: wt[e][c][r] = w[e][r][c] ----------------
__global__ __launch_bounds__(256) void k_tr(const float* __restrict__ w,
                                            short* __restrict__ wt, int R, int C) {
  __shared__ float sl[64][65];
  int e = blockIdx.z;
  const float* W = w + (size_t)e * R * C;
  short* O = wt + (size_t)e * R * C;
  int c0 = blockIdx.x * 64, r0 = blockIdx.y * 64;
  int t = threadIdx.x;
  int lr = t >> 4, lc4 = (t & 15) * 4;
#pragma unroll
  for (int i = 0; i < 4; i++) {
    float4 v = *(const float4*)&W[(size_t)(r0 + lr + i * 16) * C + c0 + lc4];
    sl[lr + i * 16][lc4 + 0] = v.x;
    sl[lr + i * 16][lc4 + 1] = v.y;
    sl[lr + i * 16][lc4 + 2] = v.z;
    sl[lr + i * 16][lc4 + 3] = v.w;
  }
  __syncthreads();
#pragma unroll
  for (int i = 0; i < 4; i++) {
    int oc = lr + i * 16;
    short4v s;
#pragma unroll
    for (int j = 0; j < 4; j++) s[j] = f2bf(sl[lc4 + j][oc]);
    *(short4v*)&O[(size_t)(c0 + oc) * R + r0 + lc4] = s;
  }
}

// ---------------- gating (fp32 x for exact top-k selection) ----------------
__global__ __launch_bounds__(256) void k_gate(const float* __restrict__ x,
    const float* __restrict__ gw, const float* __restrict__ gb,
    int2* __restrict__ toke, float2* __restrict__ tokw, int* __restrict__ cnt) {
  __shared__ float sg[NEXP * DDIM];
  for (int i = threadIdx.x; i < NEXP * DDIM; i += 256) {
    int e = i >> 10, d = i & (DDIM - 1);
    sg[i] = gw[d * NEXP + e];
  }
  __syncthreads();
  int wave = threadIdx.x >> 6, lane = threadIdx.x & 63;
  int tok0 = blockIdx.x * 32;
  for (int tt = wave; tt < 32; tt += 4) {
    int tok = tok0 + tt;
    float p[NEXP];
#pragma unroll
    for (int e = 0; e < NEXP; e++) p[e] = 0.f;
#pragma unroll
    for (int c = 0; c < 4; c++) {
      int d = c * 256 + lane * 4;
      float4 xv = *(const float4*)&x[(size_t)tok * DDIM + d];
#pragma unroll
      for (int e = 0; e < NEXP; e++) {
        float4 g = *(const float4*)&sg[e * DDIM + d];
        p[e] += xv.x * g.x + xv.y * g.y + xv.z * g.z + xv.w * g.w;
      }
    }
#pragma unroll
    for (int off = 32; off; off >>= 1)
#pragma unroll
      for (int e = 0; e < NEXP; e++) p[e] += __shfl_xor(p[e], off);
    if (lane == 0) {
      float l[NEXP];
#pragma unroll
      for (int e = 0; e < NEXP; e++) l[e] = p[e] + gb[e];
      int i0 = 0;
#pragma unroll
      for (int e = 1; e < NEXP; e++) if (l[e] > l[i0]) i0 = e;
      int i1 = (i0 == 0) ? 1 : 0;
#pragma unroll
      for (int e = 0; e < NEXP; e++) if (e != i0 && l[e] > l[i1]) i1 = e;
      float ex = expf(l[i1] - l[i0]);
      float w0 = 1.f / (1.f + ex);
      toke[tok] = make_int2(i0, i1);
      tokw[tok] = make_float2(w0, 1.f - w0);
      atomicAdd(&cnt[i0], 1);
      atomicAdd(&cnt[i1], 1);
    }
  }
}

// ---------------- routing plan ----------------
__global__ void k_plan(const int* __restrict__ cnt, int* __restrict__ pbase,
                       int* __restrict__ texp) {
  if (threadIdx.x == 0 && blockIdx.x == 0) {
    int base = 0;
    for (int e = 0; e < NEXP; e++) {
      pbase[e] = base;
      int pc = (cnt[e] + BM - 1) & ~(BM - 1);
      for (int t = base / BM; t < (base + pc) / BM; ++t) texp[t] = e;
      base += pc;
    }
    for (int t = base / BM; t < MAXTILES; ++t) texp[t] = -1;
  }
}

__global__ __launch_bounds__(256) void k_scatter(const int2* __restrict__ toke,
    const float2* __restrict__ tokw, const int* __restrict__ pbase,
    int* __restrict__ fill, int* __restrict__ rtok, float* __restrict__ rwgt) {
  int tok = blockIdx.x * 256 + threadIdx.x;
  if (tok >= T_TOK) return;
  int2 te = toke[tok];
  float2 tw = tokw[tok];
  int s0 = atomicAdd(&fill[te.x], 1);
  rtok[pbase[te.x] + s0] = tok; rwgt[pbase[te.x] + s0] = tw.x;
  int s1 = atomicAdd(&fill[te.y], 1);
  rtok[pbase[te.y] + s1] = tok; rwgt[pbase[te.y] + s1] = tw.y;
}

// ============== 128x128-tile grouped GEMM, 4 waves (2M x 2N, 64x64/wave) ==========
// m97-structure regime: acc[4][4]=64 AGPR, __launch_bounds__(256,4) caps unified
// regs at 128/wave -> 4 waves/SIMD -> 4 INDEPENDENT 4-wave blocks/CU. LDS 32 KiB
// single-buffered (A[128][64]+B[128][64] shorts), XOR-8 swizzled slots (16B slot s
// of row r holds global slot s^(r&7); 0 bank conflicts). Simple loop: STAGE (8
// gld16/wave) -> vmcnt(0) -> barrier -> 32 MFMA (setprio'd) -> barrier; the other
// 3 resident blocks cover each drain (m114 implicit overlap).

#define STG(ko) { \
  gld16(sA[0] + (ko), &AL[(0 * 32 + wid * 8) * BK]); \
  gld16(sA[1] + (ko), &AL[(1 * 32 + wid * 8) * BK]); \
  gld16(sA[2] + (ko), &AL[(2 * 32 + wid * 8) * BK]); \
  gld16(sA[3] + (ko), &AL[(3 * 32 + wid * 8) * BK]); \
  gld16(sB[0] + (ko), &BL[(0 * 32 + wid * 8) * BK]); \
  gld16(sB[1] + (ko), &BL[(1 * 32 + wid * 8) * BK]); \
  gld16(sB[2] + (ko), &BL[(2 * 32 + wid * 8) * BK]); \
  gld16(sB[3] + (ko), &BL[(3 * 32 + wid * 8) * BK]); }

#define MFMA_TILE { \
  __builtin_amdgcn_s_setprio(1); \
  _Pragma("unroll") \
  for (int s = 0; s < 2; ++s) { \
    int xo = ((s * 4 + kg) ^ x7) << 3; \
    short8 af[4], bg[4]; \
    _Pragma("unroll") \
    for (int i = 0; i < 4; i++) af[i] = *(short8*)&AL[(wm + i * 16 + lr) * BK + xo]; \
    _Pragma("unroll") \
    for (int j = 0; j < 4; j++) bg[j] = *(short8*)&BL[(wn + j * 16 + lr) * BK + xo]; \
    _Pragma("unroll") \
    for (int i = 0; i < 4; i++) \
    _Pragma("unroll") \
    for (int j = 0; j < 4; j++) \
      acc[i][j] = __builtin_amdgcn_mfma_f32_16x16x32_bf16(af[i], bg[j], acc[i][j], 0, 0, 0); \
  } \
  __builtin_amdgcn_s_setprio(0); }

#define GEMM_LOOP(NKv) \
  for (int kt = 0; kt < (NKv); ++kt) { \
    STG(kt * BK); \
    asm volatile("s_waitcnt vmcnt(0)" ::: "memory"); \
    __syncthreads(); \
    MFMA_TILE; \
    __syncthreads(); \
  }

// ---------------- stage 1: h = gelu(x @ w1[e] + b1[e]) ----------------
// grid (HDIM/128 = 32, nt), 256 threads. w1t = [e][n(H)][k(D)] bf16.
__global__ __launch_bounds__(256, 4) void k_ffn1(const short* __restrict__ xb,
    const short* __restrict__ w1t, const float* __restrict__ b1,
    const int* __restrict__ rtok, const int* __restrict__ texp,
    int tile_base, short* __restrict__ hbuf) {
  int tl = blockIdx.y;
  int tm = tile_base + tl;
  int e = texp[tm];
  if (e < 0) return;
  int n0 = blockIdx.x * BN;
  const short* W = w1t + (size_t)e * HDIM * DDIM;
  __shared__ short AL[BM * BK];   // 16 KiB
  __shared__ short BL[BN * BK];   // 16 KiB
  int t = threadIdx.x, wid = t >> 6, lane = t & 63;
  int sr8 = lane >> 3, slot = lane & 7;
  int swz = (slot ^ sr8) * 8;
  const short* sA[4]; const short* sB[4];
#pragma unroll
  for (int i = 0; i < 4; i++) {
    int r = i * 32 + wid * 8 + sr8;
    int tok = rtok[tm * BM + r]; if (tok < 0) tok = 0;   // pads read row0 (dropped in ffn2)
    sA[i] = xb + (size_t)tok * DDIM + swz;
    sB[i] = W + (size_t)(n0 + r) * DDIM + swz;
  }

  f32x4 acc[4][4];
#pragma unroll
  for (int i = 0; i < 4; i++)
#pragma unroll
    for (int j = 0; j < 4; j++) acc[i][j] = (f32x4){0.f, 0.f, 0.f, 0.f};

  int wm = (wid >> 1) * 64, wn = (wid & 1) * 64;
  int lr = lane & 15, kg = lane >> 4, x7 = lr & 7;

  GEMM_LOOP(DDIM / BK)   // 16

#pragma unroll
  for (int j = 0; j < 4; j++) {
    int gcol = n0 + wn + j * 16 + lr;
    float bias = b1[e * HDIM + gcol];
#pragma unroll
    for (int i = 0; i < 4; i++) {
      int rl = wm + i * 16 + kg * 4;
#pragma unroll
      for (int r = 0; r < 4; r++) {
        float v = acc[i][j][r] + bias;
        v = 0.5f * v * (1.f + erff(v * 0.70710678118f));
        hbuf[(size_t)(tl * BM + rl + r) * HDIM + gcol] = f2bf(v);
      }
    }
  }
}

// ---------------- stage 2: out[tok] += wgt * (h @ w2[e] + b2[e]) ----------------
// grid (DDIM/128 = 8, KS2, nt), 256 threads. w2t = [e][n(D)][k(H)] bf16. Split-K over H.
__global__ __launch_bounds__(256, 4) void k_ffn2(const short* __restrict__ hbuf,
    const short* __restrict__ w2t, const float* __restrict__ b2,
    const int* __restrict__ rtok, const float* __restrict__ rwgt,
    const int* __restrict__ texp, int tile_base, float* __restrict__ out) {
  int tl = blockIdx.z;
  int tm = tile_base + tl;
  int e = texp[tm];
  if (e < 0) return;
  int kc = blockIdx.y;
  int n0 = blockIdx.x * BN;
  const short* W = w2t + (size_t)e * DDIM * HDIM;
  __shared__ short AL[BM * BK];
  __shared__ short BL[BN * BK];
  int t = threadIdx.x, wid = t >> 6, lane = t & 63;
  int sr8 = lane >> 3, slot = lane & 7;
  int swz = (slot ^ sr8) * 8;
  const int NK = HDIM / BK / KS2;            // 32
  int kbase = kc * NK * BK;
  const short* sA[4]; const short* sB[4];
#pragma unroll
  for (int i = 0; i < 4; i++) {
    int r = i * 32 + wid * 8 + sr8;
    sA[i] = hbuf + (size_t)(tl * BM + r) * HDIM + kbase + swz;
    sB[i] = W + (size_t)(n0 + r) * HDIM + kbase + swz;
  }

  f32x4 acc[4][4];
#pragma unroll
  for (int i = 0; i < 4; i++)
#pragma unroll
    for (int j = 0; j < 4; j++) acc[i][j] = (f32x4){0.f, 0.f, 0.f, 0.f};

  int wm = (wid >> 1) * 64, wn = (wid & 1) * 64;
  int lr = lane & 15, kg = lane >> 4, x7 = lr & 7;

  GEMM_LOOP(NK)

#pragma unroll
  for (int j = 0; j < 4; j++) {
    int gcol = n0 + wn + j * 16 + lr;
    float bias = (kc == 0) ? b2[e * DDIM + gcol] : 0.f;
#pragma unroll
    for (int i = 0; i < 4; i++) {
      int rl = wm + i * 16 + kg * 4;
#pragma unroll
      for (int r = 0; r < 4; r++) {
        int grow = tm * BM + rl + r;
        int tok = rtok[grow];
        if (tok >= 0) {
          float v = (acc[i][j][r] + bias) * rwgt[grow];
          atomicAdd(&out[(size_t)tok * DDIM + gcol], v);
        }
      }
    }
  }
}

extern "C" void kernel_launch(void* const* d_in, const int* in_sizes, int n_in,
                              void* d_out, int out_size, void* d_ws, size_t ws_size,
                              hipStream_t stream) {
  const float* x  = (const float*)d_in[0];
  const float* gw = (const float*)d_in[1];
  const float* gb = (const float*)d_in[2];
  const float* w1 = (const float*)d_in[3];
  const float* b1 = (const float*)d_in[4];
  const float* w2 = (const float*)d_in[5];
  const float* b2 = (const float*)d_in[6];
  float* out = (float*)d_out;
  char* ws = (char*)d_ws;

  // ws layout: 1MB header | w1t 67.1MB | w2t 67.1MB | xb 16.8MB | hbuf (chunked)
  int*    cnt   = (int*)(ws + 0);
  int*    fill  = (int*)(ws + 32);
  int*    pbase = (int*)(ws + 64);
  int*    texp  = (int*)(ws + 128);
  int*    rtok  = (int*)(ws + 1024);
  float*  rwgt  = (float*)(ws + 1024 + (size_t)MAXROWS * 4);
  int2*   toke  = (int2*)(ws + 1024 + (size_t)MAXROWS * 8);
  float2* tokw  = (float2*)(ws + 1024 + (size_t)MAXROWS * 8 + (size_t)T_TOK * 8);
  size_t wbytes = (size_t)NEXP * DDIM * HDIM * 2;
  short*  w1t   = (short*)(ws + (1 << 20));
  short*  w2t   = (short*)(ws + (1 << 20) + wbytes);
  short*  xb    = (short*)(ws + (1 << 20) + 2 * wbytes);
  size_t hoff   = (1 << 20) + 2 * wbytes + (size_t)T_TOK * DDIM * 2;
  short*  hbuf  = (short*)(ws + hoff);

  size_t hcap = ws_size > hoff ? ws_size - hoff : 0;
  int tpc = (int)(hcap / ((size_t)BM * HDIM * 2));   // 1MB per tile of h
  if (tpc < 1) return;
  if (tpc > MAXTILES) tpc = MAXTILES;

  hipMemsetAsync(d_out, 0, (size_t)T_TOK * DDIM * 4, stream);
  hipMemsetAsync(ws, 0, 128, stream);
  hipMemsetAsync(rtok, 0xFF, (size_t)MAXROWS * 4, stream);

  k_tr<<<dim3(HDIM / 64, DDIM / 64, NEXP), 256, 0, stream>>>(w1, w1t, DDIM, HDIM);
  k_tr<<<dim3(DDIM / 64, HDIM / 64, NEXP), 256, 0, stream>>>(w2, w2t, HDIM, DDIM);
  k_xb<<<(T_TOK * DDIM) / (256 * 8), 256, 0, stream>>>(x, xb);

  k_gate<<<256, 256, 0, stream>>>(x, gw, gb, toke, tokw, cnt);
  k_plan<<<1, 64, 0, stream>>>(cnt, pbase, texp);
  k_scatter<<<T_TOK / 256, 256, 0, stream>>>(toke, tokw, pbase, fill, rtok, rwgt);

  for (int base = 0; base < MAXTILES; base += tpc) {
    int nt = MAXTILES - base;
    if (nt > tpc) nt = tpc;
    k_ffn1<<<dim3(HDIM / BN, nt), 256, 0, stream>>>(xb, w1t, b1, rtok, texp, base, hbuf);
    k_ffn2<<<dim3(DDIM / BN, KS2, nt), 256, 0, stream>>>(hbuf, w2t, b2, rtok, rwgt, texp, base, out);
  }
}